// Round 3
// baseline (1418.490 us; speedup 1.0000x reference)
//
#include <hip/hip_runtime.h>

typedef __bf16 bf16x8 __attribute__((ext_vector_type(8)));
typedef float f32x4 __attribute__((ext_vector_type(4)));

union BF8 { unsigned short u[8]; bf16x8 v; };

__device__ __forceinline__ unsigned short f2bf(float f){
  unsigned int u = __float_as_uint(f);
  return (unsigned short)((u + 0x7fffu + ((u >> 16) & 1u)) >> 16);
}

__device__ __forceinline__ bf16x8 load_w8(const float* __restrict__ p){
  const float4 a = *(const float4*)p;
  const float4 b = *(const float4*)(p + 4);
  BF8 r;
  r.u[0]=f2bf(a.x); r.u[1]=f2bf(a.y); r.u[2]=f2bf(a.z); r.u[3]=f2bf(a.w);
  r.u[4]=f2bf(b.x); r.u[5]=f2bf(b.y); r.u[6]=f2bf(b.z); r.u[7]=f2bf(b.w);
  return r.v;
}

__device__ __forceinline__ float sigm(float x){ return 1.f/(1.f + __expf(-x)); }
__device__ __forceinline__ float tanh_(float x){ return 2.f/(1.f + __expf(-2.f*x)) - 1.f; }

#define MFMA(a,b,c) __builtin_amdgcn_mfma_f32_16x16x32_bf16((a),(b),(c),0,0,0)

// 1024 blocks x 256 threads (4 waves). Block owns 4 batch rows (M-tile rows
// 4..15 are duplicates of 0..3 -- MFMA lanes are cheap, occupancy is not).
// 4 blocks/CU -> 4 waves/SIMD: independent blocks overlap each other's
// dependency/barrier stalls. Wave w owns hidden cols [16w,16w+16).
// State s_h/s_c: [col16][row4][hid64] bf16, swizzle hid ^ (S[row]*8),
// S={0,2,5,7} => A-frag ds_read_b128 is 2-way (free) bank aliased.
__global__ __launch_bounds__(256,4) void lstm2d_kernel(
    const float* __restrict__ x,   const float* __restrict__ Wx,
    const float* __restrict__ Wh,  const float* __restrict__ Wh2,
    const float* __restrict__ Wih, const float* __restrict__ Whh,
    const float* __restrict__ bih, const float* __restrict__ bhh,
    const float* __restrict__ Wfc, const float* __restrict__ bfc,
    float* __restrict__ out)
{
  __shared__ __align__(16) unsigned short s_h[16*4*64];    // 8 KB
  __shared__ __align__(16) unsigned short s_c[16*4*64];    // 8 KB
  __shared__ __align__(16) unsigned short s_hint[4*64];    // 512 B
  __shared__ __align__(16) float s_xh[256*4];              // 4 KB [slot][row]
  __shared__ unsigned int s_msk[4*8];                      // [row][word]
  __shared__ __align__(16) float s_logit[16];              // [row][wave]

  const int tid  = threadIdx.x;
  const int w    = tid >> 6;
  const int lane = tid & 63;
  const int l16  = lane & 15;
  const int g4   = lane >> 4;
  const int g8   = g4 * 8;
  const int rl   = l16 & 3;          // duplicated batch row for A-reads

  const float wx0 = Wx[0], wx1 = Wx[1];

  // ---- zero h/c state ----
  unsigned int* zh = (unsigned int*)s_h;
  unsigned int* zc = (unsigned int*)s_c;
  #pragma unroll
  for (int it=0; it<8; ++it){ zh[tid + it*256] = 0u; zc[tid + it*256] = 0u; }

  // ---- precompute xh for every (slot, row) ----
  const float* xg = x + blockIdx.x * 1024;
  #pragma unroll
  for (int k=0; k<4; ++k){
    const int idx = tid + k*256;          // 0..1023
    const int row = idx & 3, slot = idx >> 2;
    const int i = slot >> 4, t = slot & 15;
    const int c   = (i & 1) ? 15 - t : t;
    const int cpc = (i & 1) ? c + 1 : c - 1;
    const float xp = (t > 0) ? xg[row*256 + i*16 + cpc] : 0.f;
    const float xu = (i > 0) ? xg[row*256 + (i-1)*16 + c] : 0.f;
    s_xh[slot*4 + row] = (xp*wx0 + xu*wx1 + 1.f) * 0.5f;
  }
  // ---- mask bits ----
  if (tid < 32){
    const int row = tid >> 3, wd = tid & 7;
    unsigned int m = 0;
    for (int b=0; b<32; ++b){
      const int slot = wd*32 + b, i = slot >> 4, t = slot & 15;
      const int c = (i & 1) ? 15 - t : t;
      if (xg[row*256 + i*16 + c] > 0.f) m |= (1u << b);
    }
    s_msk[row*8 + wd] = m;
  }

  // ---- weight fragments in VGPRs ----
  bf16x8 bh[4], bc[4], bg[4][2];
  #pragma unroll
  for (int s=0;s<4;++s){
    const int n = w*16 + l16, k = s*32 + g8;
    bh[s] = load_w8(Wh  + n*128 + k);   // [0..1]=prev, [2..3]=up
    bc[s] = load_w8(Wh2 + n*128 + k);
  }
  #pragma unroll
  for (int g=0; g<4; ++g)
    #pragma unroll
    for (int s=0;s<2;++s){
      const int n = g*64 + w*16 + l16, k = s*32 + g8;
      bg[g][s] = load_w8(Whh + n*64 + k);
    }

  const float bfcd = bfc[0] - bfc[1];
  float base_[4], dvec_[4];
  #pragma unroll
  for (int g=0; g<4; ++g){
    const int cg = g*64 + w*16 + l16;
    base_[g] = bih[cg] + bhh[cg] + Wih[cg*2+1];
    dvec_[g] = Wih[cg*2+0] - Wih[cg*2+1];
  }
  const int colw = w*16 + l16;
  const float wfd = Wfc[colw] - Wfc[64 + colw];

  // swizzle: S[r] = 2r + (r>>1) -> {0,2,5,7}; offset in elements
  const int swzr  = (rl*2 + (rl>>1)) << 3;
  const int offA0 = rl*64 + ((     g8) ^ swzr);
  const int offA1 = rl*64 + ((32 + g8) ^ swzr);
  int stW[4];
  #pragma unroll
  for (int r=0;r<4;++r)
    stW[r] = r*64 + (colw ^ ((r*2 + (r>>1)) << 3));

  float lp = 0.f;
  int aa = 0;

  __syncthreads();

  f32x4 aHu, aCu;    // up-row contribution for the current slot

  for (int i=0; i<16; ++i){
    const int dir = i & 1;
    {  // row prologue: up contribution for t=0
      const int b = (dir ? 15 : 0) << 8;
      f32x4 h0 = {0,0,0,0}, cv = {0,0,0,0};
      bf16x8 ah0 = *(const bf16x8*)(s_h + b + offA0);
      bf16x8 ah1 = *(const bf16x8*)(s_h + b + offA1);
      bf16x8 ac0 = *(const bf16x8*)(s_c + b + offA0);
      bf16x8 ac1 = *(const bf16x8*)(s_c + b + offA1);
      h0 = MFMA(ah0, bh[2], h0); h0 = MFMA(ah1, bh[3], h0);
      cv = MFMA(ac0, bc[2], cv); cv = MFMA(ac1, bc[3], cv);
      aHu = h0; aCu = cv;
    }

    for (int t=0; t<16; ++t){
      const int c    = dir ? 15 - t : t;
      const int slot = i*16 + t;

      // ---------- phase 1: h_inter ----------
      f32x4 aH = aHu;
      if (t > 0){
        const int b = (dir ? c + 1 : c - 1) << 8;
        bf16x8 a0 = *(const bf16x8*)(s_h + b + offA0);
        bf16x8 a1 = *(const bf16x8*)(s_h + b + offA1);
        aH = MFMA(a0, bh[0], aH);
        aH = MFMA(a1, bh[1], aH);
      }

      // softmax finish of previous slot: wave w handles batch row w
      if (slot > 0 && lane == 0){
        const float4 v = *(const float4*)(s_logit + w*4);
        const float d  = v.x + v.y + v.z + v.w + bfcd;
        const int ps   = slot - 1;
        const int msk  = (s_msk[w*8 + (ps >> 5)] >> (ps & 31)) & 1;
        lp -= __logf(1.f + __expf(msk ? -d : d));
        aa += msk;
      }

      // hand off h_inter (rows 0..3 live in g4==0 lanes)
      if (g4 == 0){
        #pragma unroll
        for (int r=0;r<4;++r) s_hint[stW[r]] = f2bf(aH[r]);
      }

      __syncthreads();   // B1

      // ---------- phase 2 ----------
      f32x4 aC = aCu;
      if (t > 0){
        const int b = (dir ? c + 1 : c - 1) << 8;
        bf16x8 a0 = *(const bf16x8*)(s_c + b + offA0);
        bf16x8 a1 = *(const bf16x8*)(s_c + b + offA1);
        aC = MFMA(a0, bc[0], aC);
        aC = MFMA(a1, bc[1], aC);
      }

      const float4 xh4 = *(const float4*)(s_xh + slot*4);
      f32x4 accG[4];
      #pragma unroll
      for (int g=0; g<4; ++g){
        accG[g][0] = base_[g] + xh4.x * dvec_[g];
        accG[g][1] = base_[g] + xh4.y * dvec_[g];
        accG[g][2] = base_[g] + xh4.z * dvec_[g];
        accG[g][3] = base_[g] + xh4.w * dvec_[g];
      }
      bf16x8 ag0 = *(const bf16x8*)(s_hint + offA0);
      bf16x8 ag1 = *(const bf16x8*)(s_hint + offA1);
      #pragma unroll
      for (int g=0; g<4; ++g){
        accG[g] = MFMA(ag0, bg[g][0], accG[g]);
        accG[g] = MFMA(ag1, bg[g][1], accG[g]);
      }

      // prefetch next slot's up contribution (reads prev-row column only)
      if (t < 15){
        const int b = (dir ? 14 - t : t + 1) << 8;
        f32x4 h0 = {0,0,0,0}, cv = {0,0,0,0};
        bf16x8 ah0 = *(const bf16x8*)(s_h + b + offA0);
        bf16x8 ah1 = *(const bf16x8*)(s_h + b + offA1);
        bf16x8 ac0 = *(const bf16x8*)(s_c + b + offA0);
        bf16x8 ac1 = *(const bf16x8*)(s_c + b + offA1);
        h0 = MFMA(ah0, bh[2], h0); h0 = MFMA(ah1, bh[3], h0);
        cv = MFMA(ac0, bc[2], cv); cv = MFMA(ac1, bc[3], cv);
        aHu = h0; aCu = cv;
      }

      // epilogue: activations + state write + FC logit-diff partials
      float pd[4];
      const int cb = c << 8;
      #pragma unroll
      for (int r=0;r<4;++r){
        const float ig = accG[0][r], fg = accG[1][r], gg = accG[2][r], og = accG[3][r];
        const float cn = sigm(fg)*aC[r] + sigm(ig)*tanh_(gg);
        const float hn = sigm(og)*tanh_(cn);
        if (g4 == 0){
          s_h[cb + stW[r]] = f2bf(hn);
          s_c[cb + stW[r]] = f2bf(cn);
        }
        pd[r] = hn * wfd;
      }
      #pragma unroll
      for (int off=1; off<16; off<<=1){
        #pragma unroll
        for (int r=0;r<4;++r) pd[r] += __shfl_xor(pd[r], off);
      }
      if (lane == 0){
        #pragma unroll
        for (int r=0;r<4;++r) s_logit[r*4 + w] = pd[r];
      }

      __syncthreads();   // B2
    }
  }

  // finish slot 255 (cell (15,0)), rec fix, store
  if (lane == 0){
    const float4 v = *(const float4*)(s_logit + w*4);
    const float d  = v.x + v.y + v.z + v.w + bfcd;
    const int msk  = (s_msk[w*8 + 7] >> 31) & 1;
    const float contrib = -__logf(1.f + __expf(msk ? -d : d));
    lp += contrib; aa += msk;
    if (aa == 1 && msk) lp -= contrib;   // factor = 1 - mask[15,0] when aa==1
    out[blockIdx.x*4 + w] = lp;
  }
}

extern "C" void kernel_launch(void* const* d_in, const int* in_sizes, int n_in,
                              void* d_out, int out_size, void* d_ws, size_t ws_size,
                              hipStream_t stream) {
  const float* x   = (const float*)d_in[0];
  const float* Wx  = (const float*)d_in[1];
  const float* Wh  = (const float*)d_in[2];
  const float* Wh2 = (const float*)d_in[3];
  const float* Wih = (const float*)d_in[4];
  const float* Whh = (const float*)d_in[5];
  const float* bih = (const float*)d_in[6];
  const float* bhh = (const float*)d_in[7];
  const float* Wfc = (const float*)d_in[8];
  const float* bfc = (const float*)d_in[9];
  float* out = (float*)d_out;
  lstm2d_kernel<<<dim3(1024), dim3(256), 0, stream>>>(
      x, Wx, Wh, Wh2, Wih, Whh, bih, bhh, Wfc, bfc, out);
}

// Round 4
// 258.526 us; speedup vs baseline: 5.4868x; 5.4868x over previous
//
#include <hip/hip_runtime.h>

typedef __bf16 bf16x8 __attribute__((ext_vector_type(8)));
typedef float f32x4 __attribute__((ext_vector_type(4)));

#define MFMA(a,b,c) __builtin_amdgcn_mfma_f32_16x16x32_bf16((a),(b),(c),0,0,0)

__device__ __forceinline__ float rcp_(float x){ return __builtin_amdgcn_rcpf(x); }

// ---------------- prep: fold Whh@Wh_p / Whh@Wh_u, build bf16 B-frag table ----
// tbl layout: per main-kernel tid (0..255): 22 frags x 8 bf16 = 176 elements.
//   f 0..7  : G1[g][s]  (g=f>>1, s=f&1)  = (Whh @ Wh_p)[n][k],  x2 for g==2
//   f 8..15 : G2[g][s]                   = (Whh @ Wh_u)[n][k],  x2 for g==2
//   f 16..19: bc[s]  = Wh2[n][k], k = s*32+g8+e  (K=128 = [prev|up])
//   f 20..21: fc[s]  = Wfc[0][k] - Wfc[1][k]     (broadcast over n)
__global__ __launch_bounds__(256) void prep_kernel(
    const float* __restrict__ Wh,  const float* __restrict__ Wh2,
    const float* __restrict__ Whh, const float* __restrict__ Wfc,
    __bf16* __restrict__ tbl)
{
  const int idx = blockIdx.x*256 + threadIdx.x;
  if (idx >= 256*176) return;
  const int e = idx & 7, f = (idx >> 3) % 22, t = idx / 176;
  const int w = t >> 6, lane = t & 63, l16 = lane & 15, g8 = (lane >> 4) * 8;
  float val;
  if (f < 16){
    const int g = (f >> 1) & 3, s = f & 1, half = f >> 3;
    const int n = g*64 + w*16 + l16;
    const int k = s*32 + g8 + e;
    const float* whcol = Wh + half*64 + k;        // Wh[j][half*64+k], stride 128
    float acc = 0.f;
    for (int j=0; j<64; ++j) acc += Whh[n*64 + j] * whcol[j*128];
    val = (g == 2) ? 2.f*acc : acc;
  } else if (f < 20){
    const int s = f - 16;
    const int n = w*16 + l16;
    const int k = s*32 + g8 + e;
    val = Wh2[n*128 + k];
  } else {
    const int s = f - 20;
    const int k = s*32 + g8 + e;
    val = Wfc[k] - Wfc[64 + k];
  }
  tbl[t*176 + f*8 + e] = (__bf16)val;
}

// ---------------- main: 256 blocks x 256 threads (4 waves, 16 batch rows) ----
// Wave w owns hidden cols [16w,16w+16) of all 4 gates and of c_inter.
// gates(t) = h_prev@G1.T + h_up@G2.T + xh-init  -- single GEMM level, so the
// per-cell chain is: ds_read h(cp) -> 2-MFMA chain -> activations -> write ->
// ONE barrier. Up-contributions (G2/c_up) prefetched one slot ahead; FC
// logit-diff folded into 2 MFMAs on the same A-frags (no shuffles, no s_logit).
__global__ __launch_bounds__(256,1) void lstm2d_kernel(
    const float* __restrict__ x,   const float* __restrict__ Wx,
    const float* __restrict__ Wih,
    const float* __restrict__ bih, const float* __restrict__ bhh,
    const float* __restrict__ bfc,
    const __bf16* __restrict__ tbl,
    float* __restrict__ out)
{
  __shared__ __align__(16) __bf16 s_h[16*16*64];   // [col][row][hid], 32 KB
  __shared__ __align__(16) __bf16 s_c[16*16*64];   // 32 KB
  __shared__ __align__(16) float  s_xh[256*16];    // [slot][row], 16 KB
  __shared__ unsigned int s_msk[16*8];             // [row][word]

  const int tid  = threadIdx.x;
  const int w    = tid >> 6;
  const int lane = tid & 63;
  const int l16  = lane & 15;
  const int g4   = lane >> 4;
  const int g8   = g4 * 8;

  const float wx0 = Wx[0], wx1 = Wx[1];

  // zero state
  unsigned int* zh = (unsigned int*)s_h;
  unsigned int* zc = (unsigned int*)s_c;
  #pragma unroll
  for (int it=0; it<32; ++it){ zh[tid + it*256] = 0u; zc[tid + it*256] = 0u; }

  // xh precompute: xh = (x_prev*wx0 + x_up*wx1 + 1)/2 per (slot,row)
  const float* xg = x + blockIdx.x * 4096;
  #pragma unroll
  for (int k=0; k<16; ++k){
    const int idx = tid + k*256;
    const int row = idx & 15, slot = idx >> 4;
    const int i = slot >> 4, t = slot & 15;
    const int c   = (i & 1) ? 15 - t : t;
    const int cpc = (i & 1) ? c + 1 : c - 1;
    const float xp = (t > 0) ? xg[row*256 + i*16 + cpc] : 0.f;
    const float xu = (i > 0) ? xg[row*256 + (i-1)*16 + c] : 0.f;
    s_xh[slot*16 + row] = (xp*wx0 + xu*wx1 + 1.f) * 0.5f;
  }
  // mask bits: x>0 at each slot's own cell
  if (tid < 128){
    const int row = tid >> 3, wd = tid & 7;
    unsigned int m = 0;
    for (int b=0; b<32; ++b){
      const int slot = wd*32 + b, i = slot >> 4, t = slot & 15;
      const int c = (i & 1) ? 15 - t : t;
      if (xg[row*256 + i*16 + c] > 0.f) m |= (1u << b);
    }
    s_msk[row*8 + wd] = m;
  }

  // weight fragments from prep table (identical addresses across blocks -> L2)
  const __bf16* tb = tbl + tid*176;
  bf16x8 G1f[4][2], G2f[4][2], bcf[4], fcB[2];
  #pragma unroll
  for (int g=0; g<4; ++g)
    #pragma unroll
    for (int s=0; s<2; ++s){
      G1f[g][s] = *(const bf16x8*)(tb + (g*2+s)*8);
      G2f[g][s] = *(const bf16x8*)(tb + 64 + (g*2+s)*8);
    }
  #pragma unroll
  for (int s=0; s<4; ++s) bcf[s] = *(const bf16x8*)(tb + 128 + s*8);
  #pragma unroll
  for (int s=0; s<2; ++s) fcB[s] = *(const bf16x8*)(tb + 160 + s*8);

  const float bd = bfc[0] - bfc[1];
  float base_[4], dvec_[4];
  #pragma unroll
  for (int g=0; g<4; ++g){
    const int cg = g*64 + w*16 + l16;
    const float sc = (g == 2) ? 2.f : 1.f;
    base_[g] = (bih[cg] + bhh[cg] + Wih[cg*2+1]) * sc;
    dvec_[g] = (Wih[cg*2+0] - Wih[cg*2+1]) * sc;
  }
  const int colw = w*16 + l16;

  // per-lane LDS offsets (elements)
  const int offA0 = l16*64 + ((     g8) ^ ((l16 & 7) << 3));
  const int offA1 = l16*64 + ((32 + g8) ^ ((l16 & 7) << 3));
  int stW[4];
  #pragma unroll
  for (int r=0;r<4;++r){
    const int row = g4*4 + r;
    stW[r] = row*64 + (colw ^ ((row & 7) << 3));
  }

  float lp[4] = {0.f,0.f,0.f,0.f};
  int   aa[4] = {0,0,0,0};

  __syncthreads();

  f32x4 accGu[4], aCu, aFp;

  for (int i=0; i<16; ++i){
    const int dir = i & 1;
    const int slot0 = i*16;

    // ---- row prologue: up-contribution + FC(prev slot) at column cend ----
    {
      const int b = (dir ? 15 : 0) << 10;
      bf16x8 ah0 = *(const bf16x8*)(s_h + b + offA0);
      bf16x8 ah1 = *(const bf16x8*)(s_h + b + offA1);
      bf16x8 qc0 = *(const bf16x8*)(s_c + b + offA0);
      bf16x8 qc1 = *(const bf16x8*)(s_c + b + offA1);
      const float4 xh4 = *(const float4*)(s_xh + slot0*16 + g4*4);
      #pragma unroll
      for (int g=0; g<4; ++g){
        accGu[g][0] = base_[g] + xh4.x * dvec_[g];
        accGu[g][1] = base_[g] + xh4.y * dvec_[g];
        accGu[g][2] = base_[g] + xh4.z * dvec_[g];
        accGu[g][3] = base_[g] + xh4.w * dvec_[g];
        accGu[g] = MFMA(ah0, G2f[g][0], accGu[g]);
        accGu[g] = MFMA(ah1, G2f[g][1], accGu[g]);
      }
      f32x4 z = {0.f,0.f,0.f,0.f};
      aCu = MFMA(qc0, bcf[2], z);
      aCu = MFMA(qc1, bcf[3], aCu);
      f32x4 fz = {bd,bd,bd,bd};
      fz = MFMA(ah0, fcB[0], fz);
      aFp = MFMA(ah1, fcB[1], fz);
    }

    for (int t=0; t<16; ++t){
      const int c    = dir ? 15 - t : t;
      const int slot = slot0 + t;

      f32x4 accG[4], aC, aF;
      if (t > 0){
        const int b = (dir ? c + 1 : c - 1) << 10;
        bf16x8 a0 = *(const bf16x8*)(s_h + b + offA0);
        bf16x8 a1 = *(const bf16x8*)(s_h + b + offA1);
        bf16x8 q0 = *(const bf16x8*)(s_c + b + offA0);
        bf16x8 q1 = *(const bf16x8*)(s_c + b + offA1);
        #pragma unroll
        for (int g=0; g<4; ++g){
          accG[g] = MFMA(a0, G1f[g][0], accGu[g]);
          accG[g] = MFMA(a1, G1f[g][1], accG[g]);
        }
        aC = MFMA(q0, bcf[0], aCu);
        aC = MFMA(q1, bcf[1], aC);
        f32x4 fz = {bd,bd,bd,bd};
        fz = MFMA(a0, fcB[0], fz);
        aF = MFMA(a1, fcB[1], fz);
      } else {
        #pragma unroll
        for (int g=0; g<4; ++g) accG[g] = accGu[g];
        aC = aCu; aF = aFp;
      }

      // finish previous slot's log-softmax (redundant across lanes/waves, uniform)
      if (slot > 0){
        const int ps = slot - 1;
        #pragma unroll
        for (int r=0;r<4;++r){
          const int msk = (s_msk[(g4*4+r)*8 + (ps >> 5)] >> (ps & 31)) & 1;
          const float d = aF[r];
          const float zz = msk ? -d : d;
          lp[r] -= __logf(1.f + __expf(zz));
          aa[r] += msk;
        }
      }

      // prefetch next slot's up contribution (column c(t+1): prev-row data)
      if (t < 15){
        const int bu = (dir ? 14 - t : t + 1) << 10;
        bf16x8 au0 = *(const bf16x8*)(s_h + bu + offA0);
        bf16x8 au1 = *(const bf16x8*)(s_h + bu + offA1);
        bf16x8 cu0 = *(const bf16x8*)(s_c + bu + offA0);
        bf16x8 cu1 = *(const bf16x8*)(s_c + bu + offA1);
        const float4 xh4 = *(const float4*)(s_xh + (slot+1)*16 + g4*4);
        #pragma unroll
        for (int g=0; g<4; ++g){
          accGu[g][0] = base_[g] + xh4.x * dvec_[g];
          accGu[g][1] = base_[g] + xh4.y * dvec_[g];
          accGu[g][2] = base_[g] + xh4.z * dvec_[g];
          accGu[g][3] = base_[g] + xh4.w * dvec_[g];
          accGu[g] = MFMA(au0, G2f[g][0], accGu[g]);
          accGu[g] = MFMA(au1, G2f[g][1], accGu[g]);
        }
        f32x4 z = {0.f,0.f,0.f,0.f};
        aCu = MFMA(cu0, bcf[2], z);
        aCu = MFMA(cu1, bcf[3], aCu);
      }

      // epilogue: activations + state write (g-gate prescaled by 2)
      const int cb = c << 10;
      #pragma unroll
      for (int r=0;r<4;++r){
        const float ig = accG[0][r], fg = accG[1][r], gg = accG[2][r], og = accG[3][r];
        const float si = rcp_(1.f + __expf(-ig));
        const float sf = rcp_(1.f + __expf(-fg));
        const float tg = 2.f * rcp_(1.f + __expf(-gg)) - 1.f;
        const float cn = sf * aC[r] + si * tg;
        const float so = rcp_(1.f + __expf(-og));
        const float tc = 2.f * rcp_(1.f + __expf(-2.f*cn)) - 1.f;
        const float hn = so * tc;
        s_h[cb + stW[r]] = (__bf16)hn;
        s_c[cb + stW[r]] = (__bf16)cn;
      }

      __syncthreads();
    }
  }

  // tail: FC + finish for slot 255 (cell (15,0), column 0), rec fix, store
  {
    bf16x8 a0 = *(const bf16x8*)(s_h + offA0);
    bf16x8 a1 = *(const bf16x8*)(s_h + offA1);
    f32x4 fz = {bd,bd,bd,bd};
    fz = MFMA(a0, fcB[0], fz);
    f32x4 aF = MFMA(a1, fcB[1], fz);
    #pragma unroll
    for (int r=0;r<4;++r){
      const int msk = (s_msk[(g4*4+r)*8 + 7] >> 31) & 1;
      const float d = aF[r];
      const float zz = msk ? -d : d;
      const float contrib = -__logf(1.f + __expf(zz));
      lp[r] += contrib; aa[r] += msk;
      if (aa[r] == 1 && msk) lp[r] -= contrib;   // factor = 1 - mask when aa==1
    }
    if (w == 0 && l16 == 0){
      #pragma unroll
      for (int r=0;r<4;++r) out[blockIdx.x*16 + g4*4 + r] = lp[r];
    }
  }
}

extern "C" void kernel_launch(void* const* d_in, const int* in_sizes, int n_in,
                              void* d_out, int out_size, void* d_ws, size_t ws_size,
                              hipStream_t stream) {
  const float* x   = (const float*)d_in[0];
  const float* Wx  = (const float*)d_in[1];
  const float* Wh  = (const float*)d_in[2];
  const float* Wh2 = (const float*)d_in[3];
  const float* Wih = (const float*)d_in[4];
  const float* Whh = (const float*)d_in[5];
  const float* bih = (const float*)d_in[6];
  const float* bhh = (const float*)d_in[7];
  const float* Wfc = (const float*)d_in[8];
  const float* bfc = (const float*)d_in[9];
  float* out = (float*)d_out;
  __bf16* tbl = (__bf16*)d_ws;   // 256*176*2 = 90112 B

  prep_kernel<<<dim3(176), dim3(256), 0, stream>>>(Wh, Wh2, Whh, Wfc, tbl);
  lstm2d_kernel<<<dim3(256), dim3(256), 0, stream>>>(
      x, Wx, Wih, bih, bhh, bfc, tbl, out);
}